// Round 13
// baseline (1962.229 us; speedup 1.0000x reference)
//
#include <hip/hip_runtime.h>
#include <stdint.h>

#define BB 128
#define TT 256
#define DDIM 64
#define BIGF 1e10f
#define KE 144.2695040889f     // 1/(gamma*ln2)
#define GLN2 0.0069314718056f  // gamma*ln2 (R = R' * GLN2)

// [b][diag][row] layout (K-scaled). 512 diag slots; slot 511 + invalid cells
// stay 0 (BSS, never written) — firewalled by the scan's R-select.
__device__ float g_D[(size_t)BB * 512 * TT];
__device__ float g_shape[BB], g_sumE[BB], g_sumEw[BB];
__device__ int   g_done;

__device__ __forceinline__ float ex2(float x){ float r; asm("v_exp_f32 %0, %1":"=v"(r):"v"(x)); return r; }
__device__ __forceinline__ float lg2(float x){ float r; asm("v_log_f32 %0, %1":"=v"(r):"v"(x)); return r; }
__device__ __forceinline__ float min3f(float a,float b,float c){ float r; asm("v_min3_f32 %0,%1,%2,%3":"=v"(r):"v"(a),"v"(b),"v"(c)); return r; }

// ---------------------------------------------------------------------------
// Kernel 1: pairwise squared distances (K-scaled), written in diagonal layout
// via (i,d)-PARALLELOGRAM tiles: block = 64 i x 64 d, thread = 4i x 4d, so
// each of the 4 d-outputs is one CONTIGUOUS float4 store (i consecutive).
// T strip: 127 columns c = d-i in LDS. Also resets the g_done ticket.
// ---------------------------------------------------------------------------
__global__ __launch_bounds__(256) void dist_kernel(const float* __restrict__ P,
                                                   const float* __restrict__ Q) {
    const int itile = blockIdx.x;     // i-tile 0..3
    const int dtile = blockIdx.y;     // d-tile 0..4 (D0 = I0 + 64*dtile)
    const int b     = blockIdx.z;
    const int tid   = threadIdx.x;

    if (itile == 0 && dtile == 0 && b == 0 && tid == 0) atomicExch(&g_done, 0);

    const int I0 = itile * 64;
    const int D0 = I0 + dtile * 64;
    const int cbase = dtile * 64 - 63;          // c of Tl column 0

    __shared__ float Pl[64][68];                // [k][i_loc]
    __shared__ float Tl[64][128];               // [k][c_loc], 127 cols used

    const float* Pbase = P + ((size_t)b * TT + I0) * DDIM;
    const float* Qb    = Q + (size_t)b * TT * DDIM;

    // P tile (transpose): 64 i x 16 float4
#pragma unroll
    for (int l = 0; l < 4; ++l) {
        int e = tid + l * 256;                  // 1024 float4s
        int r = e >> 4;
        int k4 = (e & 15) * 4;
        float4 pv = *reinterpret_cast<const float4*>(Pbase + r * DDIM + k4);
        Pl[k4 + 0][r] = pv.x; Pl[k4 + 1][r] = pv.y;
        Pl[k4 + 2][r] = pv.z; Pl[k4 + 3][r] = pv.w;
    }
    // T strip (transpose): 127 cols x 16 float4 (clamped; OOB cols are masked at write)
#pragma unroll
    for (int l = 0; l < 8; ++l) {
        int e = tid + l * 256;                  // 2032 float4s
        if (e < 2032) {
            int cc = e >> 4;
            int k4 = (e & 15) * 4;
            int c  = cbase + cc;
            c = c < 0 ? 0 : (c > 255 ? 255 : c);
            float4 qv = *reinterpret_cast<const float4*>(Qb + (size_t)c * DDIM + k4);
            Tl[k4 + 0][cc] = qv.x; Tl[k4 + 1][cc] = qv.y;
            Tl[k4 + 2][cc] = qv.z; Tl[k4 + 3][cc] = qv.w;
        }
    }
    __syncthreads();

    const int ti  = tid & 15;                   // i micro-index
    const int td  = tid >> 4;                   // d micro-index
    const int i0l = ti * 4;
    const int cc0 = 4 * (td - ti) + 60;         // Tl col of (s=3, tt=0); range [0,120]

    float acc[4][4] = {};                       // [s][tt]: cell (I0+i0l+s, d=D0+4td+tt)
#pragma unroll
    for (int k = 0; k < 64; ++k) {
        float4 p  = *reinterpret_cast<const float4*>(&Pl[k][i0l]);
        float4 t0 = *reinterpret_cast<const float4*>(&Tl[k][cc0]);
        float4 t1 = *reinterpret_cast<const float4*>(&Tl[k][cc0 + 4]);
        float pa[4] = {p.x, p.y, p.z, p.w};
        float tc[8] = {t0.x, t0.y, t0.z, t0.w, t1.x, t1.y, t1.z, t1.w};
#pragma unroll
        for (int s = 0; s < 4; ++s)
#pragma unroll
            for (int tt = 0; tt < 4; ++tt) {
                float df = pa[s] - tc[tt - s + 3];   // c_loc = cc0 + tt - s + 3
                acc[s][tt] = fmaf(df, df, acc[s][tt]);
            }
    }

    const int ig = I0 + i0l;
    float* Dg = g_D + (size_t)b * 512 * TT;
#pragma unroll
    for (int tt = 0; tt < 4; ++tt) {
        const int d = D0 + td * 4 + tt;
        if (d <= 510) {
            const int cmin = d - ig - 3;
            const int cmax = d - ig;
            if (cmin >= 0 && cmax <= 255) {
                float4 v = make_float4(acc[0][tt] * KE, acc[1][tt] * KE,
                                       acc[2][tt] * KE, acc[3][tt] * KE);
                *reinterpret_cast<float4*>(Dg + (size_t)d * TT + ig) = v;
            } else {
#pragma unroll
                for (int s = 0; s < 4; ++s) {
                    int c = d - (ig + s);
                    if (c >= 0 && c <= 255)
                        Dg[(size_t)d * TT + ig + s] = acc[s][tt] * KE;
                }
            }
        }
    }
}

// ---------------------------------------------------------------------------
// Kernel 2: SINGLE-PASS soft-DTW (R' + path-sum accumulators H, G), 4 skewed
// waves per batch (identical to round-12 verified structure), plus fused
// finalize: the 128th block to finish computes the scalar loss.
// ---------------------------------------------------------------------------
__global__ __launch_bounds__(256) void scan_kernel(float* __restrict__ out) {
    const int b    = blockIdx.x;
    const int tid  = threadIdx.x;
    const int w    = tid >> 6;
    const int lane = tid & 63;
    const int row  = tid;                  // 64w + lane
    const bool lane0 = (lane == 0);
    const bool lane63 = (lane == 63);

    const float* Db = g_D + (size_t)b * 512 * TT;

    __shared__ float4 ring[64][5];         // [slot][wave]; col 4 = const {BIGF,0,0}
    __shared__ float rs[128], rt2[128];
    __shared__ int lastflag;
    for (int i = tid; i < 64 * 5; i += 256)
        ring[i / 5][i % 5] = make_float4(BIGF, 0.f, 0.f, 0.f);
    __syncthreads();

    const int rcol  = (w == 0) ? 4 : (w - 1);
    const int myoff = w << 4;

    float rp1 = BIGF, rp2 = BIGF, h1 = 0.f, h2 = 0.f, g1 = 0.f, g2 = 0.f;
    float uR = BIGF, uR2 = BIGF, uH = 0.f, uH2 = 0.f, uG = 0.f, uG2 = 0.f;
    float c1  = 0.0f;                       // virtual (0,0) diag-pred; BIGF after phase 0
    float fwv = (float)(2 * row + 16 * w);  // i - j at first phase

    auto LDD = [&](int d) -> float {
        int dc = d < 0 ? 0 : (d > 511 ? 511 : d);
        return Db[(size_t)dc * TT + row];
    };

    float dstA[16], dstB[16];
#pragma unroll
    for (int k = 0; k < 16; ++k) dstA[k] = LDD(k - myoff);

    float4 rstage[16];
    float4 rcarry = make_float4(BIGF, 0.f, 0.f, 0.f);

#pragma unroll 1
    for (int g = 0; g < 35; ++g) {          // 560 phases
        const int p0 = g << 4;
#pragma unroll
        for (int k = 0; k < 16; ++k)
            rstage[k] = ring[(p0 + k - myoff - 1) & 63][rcol];
#pragma unroll
        for (int k = 0; k < 16; ++k) dstB[k] = LDD(p0 + 16 + k - myoff);
        __builtin_amdgcn_sched_barrier(0);

#pragma unroll
        for (int k = 0; k < 16; ++k) {
            const int d = p0 + k - myoff;
            const float dcur = dstA[k];
            const float4 rb1 = rstage[k];
            const float4 rb2 = (k == 0) ? rcarry : rstage[k - 1];
            const float zu = lane0 ? rb1.x : uR;
            const float Hu = lane0 ? rb1.y : uH;
            const float Gu = lane0 ? rb1.z : uG;
            const float zd = lane0 ? fminf(rb2.x, c1) : uR2;
            const float Hd = lane0 ? rb2.y : uH2;
            const float Gd = lane0 ? rb2.z : uG2;
            const float m  = min3f(zd, zu, rp1);
            const float e1 = ex2(m - zd);
            const float e2 = ex2(m - zu);
            const float e3 = ex2(m - rp1);
            const float ss = e1 + e2 + e3;
            const float ri = __builtin_amdgcn_rcpf(ss);
            const float rv = dcur + (m - lg2(ss));
            const bool valid = (unsigned)(d - row) < 256u;
            const float Rn = valid ? rv : BIGF;
            float ha = e3 * h1; ha = fmaf(e2, Hu, ha); ha = fmaf(e1, Hd, ha);
            const float Hn = fmaf(ri, ha, 1.0f);
            float ga = e3 * g1; ga = fmaf(e2, Gu, ga); ga = fmaf(e1, Gd, ga);
            const float Gn = fmaf(ri, ga, fwv * fwv);
            const float nR = __shfl_up(Rn, 1);
            const float nH = __shfl_up(Hn, 1);
            const float nG = __shfl_up(Gn, 1);
            if (lane63) ring[d & 63][w] = make_float4(Rn, Hn, Gn, 0.f);
            rp2 = rp1; rp1 = Rn; h2 = h1; h1 = Hn; g2 = g1; g1 = Gn;
            uR2 = uR; uR = nR; uH2 = uH; uH = nH; uG2 = uG; uG = nG;
            c1 = BIGF;
            fwv -= 1.0f;
        }
        rcarry = rstage[15];
#pragma unroll
        for (int k = 0; k < 16; ++k) dstA[k] = dstB[k];
        __syncthreads();
    }

    // publish per-batch results + ticket; 128th block finalizes
    if (tid == 255) {
        g_shape[b] = rp2;    // R'(255,255)
        g_sumE[b]  = h2;     // sum(E)
        g_sumEw[b] = g2;     // sum(E * (i-j)^2)
        __threadfence();
        int t = atomicAdd(&g_done, 1);
        lastflag = (t == BB - 1) ? 1 : 0;
    }
    __syncthreads();
    if (lastflag == 0) return;
    __threadfence();                          // acquire side

    if (tid < 128) {
        const int bb = tid;
        const float sh = atomicAdd(&g_shape[bb], 0.0f);   // coherent reads
        const float sE0 = atomicAdd(&g_sumE[bb], 0.0f);
        const float sW0 = atomicAdd(&g_sumEw[bb], 0.0f);
        const float shape = sh * GLN2 * (1.0f / (float)TT);
        const float sE  = sE0 * (1.0f / (float)TT);
        const float sEw = sW0 * (1.0f / (float)TT) * (1.0f / (255.0f * 255.0f));
        rs[bb]  = shape;
        rt2[bb] = sEw / fmaxf(sE, 1e-8f);
    }
    __syncthreads();
    for (int s = 64; s > 0; s >>= 1) {
        if (tid < s) { rs[tid] += rs[tid + s]; rt2[tid] += rt2[tid + s]; }
        __syncthreads();
    }
    if (tid == 0)
        out[0] = 0.5f * (rs[0] * (1.0f / (float)BB)) + 0.5f * (rt2[0] * (1.0f / (float)BB));
}

extern "C" void kernel_launch(void* const* d_in, const int* in_sizes, int n_in,
                              void* d_out, int out_size, void* d_ws, size_t ws_size,
                              hipStream_t stream) {
    (void)in_sizes; (void)n_in; (void)out_size; (void)d_ws; (void)ws_size;
    const float* preds   = (const float*)d_in[0];
    const float* targets = (const float*)d_in[1];
    float* out = (float*)d_out;

    dist_kernel<<<dim3(4, 5, BB), 256, 0, stream>>>(preds, targets);
    scan_kernel<<<BB, 256, 0, stream>>>(out);
}

// Round 14
// 125.792 us; speedup vs baseline: 15.5990x; 15.5990x over previous
//
#include <hip/hip_runtime.h>
#include <stdint.h>

#define BB 128
#define TT 256
#define DDIM 64
#define BIGF 1e10f
#define KE 144.2695040889f     // 1/(gamma*ln2)
#define GLN2 0.0069314718056f  // gamma*ln2 (R = R' * GLN2)

// [b][diag][row] layout (K-scaled). 512 diag slots; slot 511 + invalid cells
// stay 0 (BSS, never written) — firewalled by the scan's R-select.
__device__ float g_D[(size_t)BB * 512 * TT];
__device__ float g_shape[BB], g_sumE[BB], g_sumEw[BB];
__device__ int   g_done;

__device__ __forceinline__ float ex2(float x){ float r; asm("v_exp_f32 %0, %1":"=v"(r):"v"(x)); return r; }
__device__ __forceinline__ float lg2(float x){ float r; asm("v_log_f32 %0, %1":"=v"(r):"v"(x)); return r; }
__device__ __forceinline__ float min3f(float a,float b,float c){ float r; asm("v_min3_f32 %0,%1,%2,%3":"=v"(r):"v"(a),"v"(b),"v"(c)); return r; }

// ---------------------------------------------------------------------------
// Kernel 1: pairwise squared distances (K-scaled), diagonal layout.
// (Round-12 verified version: square 64x64 tiles, VGPR-lean, ~20 us.)
// Also resets the g_done ticket for the fused finalize.
// ---------------------------------------------------------------------------
__global__ __launch_bounds__(256) void dist_kernel(const float* __restrict__ P,
                                                   const float* __restrict__ Q) {
    const int rt = blockIdx.x;
    const int ct = blockIdx.y;
    const int b  = blockIdx.z;
    const int tid = threadIdx.x;

    if (rt == 0 && ct == 0 && b == 0 && tid == 0) atomicExch(&g_done, 0);

    __shared__ float Pl[64][68];
    __shared__ float Tl[64][68];

    const float* Pbase = P + ((size_t)b * TT + rt * 64) * DDIM;
    const float* Qbase = Q + ((size_t)b * TT + ct * 64) * DDIM;

#pragma unroll
    for (int it = 0; it < 4; ++it) {
        int e = (tid + it * 256) * 4;
        int r = e >> 6;
        int k = e & 63;
        float4 pv = *reinterpret_cast<const float4*>(Pbase + e);
        float4 qv = *reinterpret_cast<const float4*>(Qbase + e);
        Pl[k + 0][r] = pv.x; Pl[k + 1][r] = pv.y; Pl[k + 2][r] = pv.z; Pl[k + 3][r] = pv.w;
        Tl[k + 0][r] = qv.x; Tl[k + 1][r] = qv.y; Tl[k + 2][r] = qv.z; Tl[k + 3][r] = qv.w;
    }
    __syncthreads();

    const int r0 = (tid >> 4) * 4;
    const int c0 = (tid & 15) * 4;

    float acc[4][4] = {};
#pragma unroll
    for (int k = 0; k < 64; ++k) {
        float4 p = *reinterpret_cast<const float4*>(&Pl[k][r0]);
        float4 t = *reinterpret_cast<const float4*>(&Tl[k][c0]);
        float pa[4] = {p.x, p.y, p.z, p.w};
        float ta[4] = {t.x, t.y, t.z, t.w};
#pragma unroll
        for (int a = 0; a < 4; ++a)
#pragma unroll
            for (int c = 0; c < 4; ++c) {
                float df = pa[a] - ta[c];
                acc[a][c] = fmaf(df, df, acc[a][c]);
            }
    }

    float* Dg = g_D + (size_t)b * 512 * TT;
#pragma unroll
    for (int a = 0; a < 4; ++a)
#pragma unroll
        for (int c = 0; c < 4; ++c) {
            int i = rt * 64 + r0 + a;
            int j = ct * 64 + c0 + c;
            Dg[(size_t)(i + j) * TT + i] = acc[a][c] * KE;
        }
}

// ---------------------------------------------------------------------------
// Kernel 2: SINGLE-PASS soft-DTW (R' + path-sum accumulators H, G), 4 skewed
// waves per batch (round-12 verified structure), with ticket-fused finalize:
// the 128th block to finish computes the scalar loss (round-13 verified).
// ---------------------------------------------------------------------------
__global__ __launch_bounds__(256) void scan_kernel(float* __restrict__ out) {
    const int b    = blockIdx.x;
    const int tid  = threadIdx.x;
    const int w    = tid >> 6;
    const int lane = tid & 63;
    const int row  = tid;                  // 64w + lane
    const bool lane0 = (lane == 0);
    const bool lane63 = (lane == 63);

    const float* Db = g_D + (size_t)b * 512 * TT;

    __shared__ float4 ring[64][5];         // [slot][wave]; col 4 = const {BIGF,0,0}
    __shared__ float rs[128], rt2[128];
    __shared__ int lastflag;
    for (int i = tid; i < 64 * 5; i += 256)
        ring[i / 5][i % 5] = make_float4(BIGF, 0.f, 0.f, 0.f);
    __syncthreads();

    const int rcol  = (w == 0) ? 4 : (w - 1);
    const int myoff = w << 4;

    float rp1 = BIGF, rp2 = BIGF, h1 = 0.f, h2 = 0.f, g1 = 0.f, g2 = 0.f;
    float uR = BIGF, uR2 = BIGF, uH = 0.f, uH2 = 0.f, uG = 0.f, uG2 = 0.f;
    float c1  = 0.0f;                       // virtual (0,0) diag-pred; BIGF after phase 0
    float fwv = (float)(2 * row + 16 * w);  // i - j at first phase

    auto LDD = [&](int d) -> float {
        int dc = d < 0 ? 0 : (d > 511 ? 511 : d);
        return Db[(size_t)dc * TT + row];
    };

    float dstA[16], dstB[16];
#pragma unroll
    for (int k = 0; k < 16; ++k) dstA[k] = LDD(k - myoff);

    float4 rstage[16];
    float4 rcarry = make_float4(BIGF, 0.f, 0.f, 0.f);

#pragma unroll 1
    for (int g = 0; g < 35; ++g) {          // 560 phases
        const int p0 = g << 4;
#pragma unroll
        for (int k = 0; k < 16; ++k)
            rstage[k] = ring[(p0 + k - myoff - 1) & 63][rcol];
#pragma unroll
        for (int k = 0; k < 16; ++k) dstB[k] = LDD(p0 + 16 + k - myoff);
        __builtin_amdgcn_sched_barrier(0);

#pragma unroll
        for (int k = 0; k < 16; ++k) {
            const int d = p0 + k - myoff;
            const float dcur = dstA[k];
            const float4 rb1 = rstage[k];
            const float4 rb2 = (k == 0) ? rcarry : rstage[k - 1];
            const float zu = lane0 ? rb1.x : uR;
            const float Hu = lane0 ? rb1.y : uH;
            const float Gu = lane0 ? rb1.z : uG;
            const float zd = lane0 ? fminf(rb2.x, c1) : uR2;
            const float Hd = lane0 ? rb2.y : uH2;
            const float Gd = lane0 ? rb2.z : uG2;
            const float m  = min3f(zd, zu, rp1);
            const float e1 = ex2(m - zd);
            const float e2 = ex2(m - zu);
            const float e3 = ex2(m - rp1);
            const float ss = e1 + e2 + e3;
            const float ri = __builtin_amdgcn_rcpf(ss);
            const float rv = dcur + (m - lg2(ss));
            const bool valid = (unsigned)(d - row) < 256u;
            const float Rn = valid ? rv : BIGF;
            float ha = e3 * h1; ha = fmaf(e2, Hu, ha); ha = fmaf(e1, Hd, ha);
            const float Hn = fmaf(ri, ha, 1.0f);
            float ga = e3 * g1; ga = fmaf(e2, Gu, ga); ga = fmaf(e1, Gd, ga);
            const float Gn = fmaf(ri, ga, fwv * fwv);
            const float nR = __shfl_up(Rn, 1);
            const float nH = __shfl_up(Hn, 1);
            const float nG = __shfl_up(Gn, 1);
            if (lane63) ring[d & 63][w] = make_float4(Rn, Hn, Gn, 0.f);
            rp2 = rp1; rp1 = Rn; h2 = h1; h1 = Hn; g2 = g1; g1 = Gn;
            uR2 = uR; uR = nR; uH2 = uH; uH = nH; uG2 = uG; uG = nG;
            c1 = BIGF;
            fwv -= 1.0f;
        }
        rcarry = rstage[15];
#pragma unroll
        for (int k = 0; k < 16; ++k) dstA[k] = dstB[k];
        __syncthreads();
    }

    // publish per-batch results + ticket; 128th block finalizes
    if (tid == 255) {
        g_shape[b] = rp2;    // R'(255,255)
        g_sumE[b]  = h2;     // sum(E)
        g_sumEw[b] = g2;     // sum(E * (i-j)^2)
        __threadfence();
        int t = atomicAdd(&g_done, 1);
        lastflag = (t == BB - 1) ? 1 : 0;
    }
    __syncthreads();
    if (lastflag == 0) return;
    __threadfence();                          // acquire side

    if (tid < 128) {
        const int bb = tid;
        const float sh  = atomicAdd(&g_shape[bb], 0.0f);   // coherent reads
        const float sE0 = atomicAdd(&g_sumE[bb], 0.0f);
        const float sW0 = atomicAdd(&g_sumEw[bb], 0.0f);
        const float shape = sh * GLN2 * (1.0f / (float)TT);
        const float sE  = sE0 * (1.0f / (float)TT);
        const float sEw = sW0 * (1.0f / (float)TT) * (1.0f / (255.0f * 255.0f));
        rs[bb]  = shape;
        rt2[bb] = sEw / fmaxf(sE, 1e-8f);
    }
    __syncthreads();
    for (int s = 64; s > 0; s >>= 1) {
        if (tid < s) { rs[tid] += rs[tid + s]; rt2[tid] += rt2[tid + s]; }
        __syncthreads();
    }
    if (tid == 0)
        out[0] = 0.5f * (rs[0] * (1.0f / (float)BB)) + 0.5f * (rt2[0] * (1.0f / (float)BB));
}

extern "C" void kernel_launch(void* const* d_in, const int* in_sizes, int n_in,
                              void* d_out, int out_size, void* d_ws, size_t ws_size,
                              hipStream_t stream) {
    (void)in_sizes; (void)n_in; (void)out_size; (void)d_ws; (void)ws_size;
    const float* preds   = (const float*)d_in[0];
    const float* targets = (const float*)d_in[1];
    float* out = (float*)d_out;

    dist_kernel<<<dim3(4, 4, BB), 256, 0, stream>>>(preds, targets);
    scan_kernel<<<BB, 256, 0, stream>>>(out);
}

// Round 15
// 120.149 us; speedup vs baseline: 16.3317x; 1.0470x over previous
//
#include <hip/hip_runtime.h>
#include <stdint.h>

#define BB 128
#define TT 256
#define DDIM 64
#define BIGF 1e10f
#define KE 144.2695040889f     // 1/(gamma*ln2)
#define GLN2 0.0069314718056f  // gamma*ln2 (R = R' * GLN2)

// [b][diag][row] layout (K-scaled). 512 diag slots; slot 511 + invalid cells
// stay 0 (BSS, never written) — firewalled by the scan's R-select.
__device__ float g_D[(size_t)BB * 512 * TT];
__device__ float g_shape[BB], g_sumE[BB], g_sumEw[BB];

__device__ __forceinline__ float ex2(float x){ float r; asm("v_exp_f32 %0, %1":"=v"(r):"v"(x)); return r; }
__device__ __forceinline__ float lg2(float x){ float r; asm("v_log_f32 %0, %1":"=v"(r):"v"(x)); return r; }
__device__ __forceinline__ float min3f(float a,float b,float c){ float r; asm("v_min3_f32 %0,%1,%2,%3":"=v"(r):"v"(a),"v"(b),"v"(c)); return r; }

// ---------------------------------------------------------------------------
// Kernel 1: pairwise squared distances (K-scaled), diagonal layout.
// (Round-12 verified: square 64x64 tiles, VGPR-lean.)
// ---------------------------------------------------------------------------
__global__ __launch_bounds__(256) void dist_kernel(const float* __restrict__ P,
                                                   const float* __restrict__ Q) {
    const int rt = blockIdx.x;
    const int ct = blockIdx.y;
    const int b  = blockIdx.z;
    const int tid = threadIdx.x;

    __shared__ float Pl[64][68];
    __shared__ float Tl[64][68];

    const float* Pbase = P + ((size_t)b * TT + rt * 64) * DDIM;
    const float* Qbase = Q + ((size_t)b * TT + ct * 64) * DDIM;

#pragma unroll
    for (int it = 0; it < 4; ++it) {
        int e = (tid + it * 256) * 4;
        int r = e >> 6;
        int k = e & 63;
        float4 pv = *reinterpret_cast<const float4*>(Pbase + e);
        float4 qv = *reinterpret_cast<const float4*>(Qbase + e);
        Pl[k + 0][r] = pv.x; Pl[k + 1][r] = pv.y; Pl[k + 2][r] = pv.z; Pl[k + 3][r] = pv.w;
        Tl[k + 0][r] = qv.x; Tl[k + 1][r] = qv.y; Tl[k + 2][r] = qv.z; Tl[k + 3][r] = qv.w;
    }
    __syncthreads();

    const int r0 = (tid >> 4) * 4;
    const int c0 = (tid & 15) * 4;

    float acc[4][4] = {};
#pragma unroll
    for (int k = 0; k < 64; ++k) {
        float4 p = *reinterpret_cast<const float4*>(&Pl[k][r0]);
        float4 t = *reinterpret_cast<const float4*>(&Tl[k][c0]);
        float pa[4] = {p.x, p.y, p.z, p.w};
        float ta[4] = {t.x, t.y, t.z, t.w};
#pragma unroll
        for (int a = 0; a < 4; ++a)
#pragma unroll
            for (int c = 0; c < 4; ++c) {
                float df = pa[a] - ta[c];
                acc[a][c] = fmaf(df, df, acc[a][c]);
            }
    }

    float* Dg = g_D + (size_t)b * 512 * TT;
#pragma unroll
    for (int a = 0; a < 4; ++a)
#pragma unroll
        for (int c = 0; c < 4; ++c) {
            int i = rt * 64 + r0 + a;
            int j = ct * 64 + c0 + c;
            Dg[(size_t)(i + j) * TT + i] = acc[a][c] * KE;
        }
}

// ---------------------------------------------------------------------------
// Kernel 2: SINGLE-PASS soft-DTW (R' + path-sum accumulators H, G), spread
// across 4 skewed waves per batch (round-12 verified, measured 91 us).
// Wave w owns rows 64w..64w+63 (1 row/lane); at phase p computes diag
// d = p - 16w. Cross-wave boundary via 64-slot LDS ring, staged per group.
// One __syncthreads per 16 phases. Branchless; single pass; no R/W storage.
// ---------------------------------------------------------------------------
__global__ __launch_bounds__(256) void scan_kernel() {
    const int b    = blockIdx.x;
    const int tid  = threadIdx.x;
    const int w    = tid >> 6;
    const int lane = tid & 63;
    const int row  = tid;                  // 64w + lane
    const bool lane0  = (lane == 0);
    const bool lane63 = (lane == 63);

    const float* Db = g_D + (size_t)b * 512 * TT;

    __shared__ float4 ring[64][5];         // [slot][wave]; col 4 = const {BIGF,0,0}
    for (int i = tid; i < 64 * 5; i += 256)
        ring[i / 5][i % 5] = make_float4(BIGF, 0.f, 0.f, 0.f);
    __syncthreads();

    const int rcol  = (w == 0) ? 4 : (w - 1);
    const int myoff = w << 4;

    // per-row state at diag d-1 / d-2
    float rp1 = BIGF, rp2 = BIGF, h1 = 0.f, h2 = 0.f, g1 = 0.f, g2 = 0.f;
    // shfl pipeline: row-1 values at d-1 (uX) and d-2 (uX2)
    float uR = BIGF, uR2 = BIGF, uH = 0.f, uH2 = 0.f, uG = 0.f, uG2 = 0.f;
    float c1  = 0.0f;                       // virtual (0,0) diag-pred; BIGF after phase 0
    float fwv = (float)(2 * row + 16 * w);  // i - j at first phase

    auto LDD = [&](int d) -> float {
        int dc = d < 0 ? 0 : (d > 511 ? 511 : d);
        return Db[(size_t)dc * TT + row];
    };

    float dstA[16], dstB[16];
#pragma unroll
    for (int k = 0; k < 16; ++k) dstA[k] = LDD(k - myoff);

    float4 rstage[16];
    float4 rcarry = make_float4(BIGF, 0.f, 0.f, 0.f);

#pragma unroll 1
    for (int g = 0; g < 35; ++g) {          // 560 phases
        const int p0 = g << 4;
        // stage ring entries (boundary row at d-1 for each phase of this group)
#pragma unroll
        for (int k = 0; k < 16; ++k)
            rstage[k] = ring[(p0 + k - myoff - 1) & 63][rcol];
        // prefetch D for next group (consumed after next barrier)
#pragma unroll
        for (int k = 0; k < 16; ++k) dstB[k] = LDD(p0 + 16 + k - myoff);
        __builtin_amdgcn_sched_barrier(0);

#pragma unroll
        for (int k = 0; k < 16; ++k) {
            const int d = p0 + k - myoff;
            const float dcur = dstA[k];
            const float4 rb1 = rstage[k];                         // boundary @ d-1
            const float4 rb2 = (k == 0) ? rcarry : rstage[k - 1]; // boundary @ d-2
            // preds: up (i-1,j)@d-1, diag (i-1,j-1)@d-2, left (i,j-1)@d-1
            const float zu = lane0 ? rb1.x : uR;
            const float Hu = lane0 ? rb1.y : uH;
            const float Gu = lane0 ? rb1.z : uG;
            const float zd = lane0 ? fminf(rb2.x, c1) : uR2;
            const float Hd = lane0 ? rb2.y : uH2;
            const float Gd = lane0 ? rb2.z : uG2;
            const float m  = min3f(zd, zu, rp1);
            const float e1 = ex2(m - zd);      // diag weight (unnorm)
            const float e2 = ex2(m - zu);      // up
            const float e3 = ex2(m - rp1);     // left
            const float ss = e1 + e2 + e3;
            const float ri = __builtin_amdgcn_rcpf(ss);
            const float rv = dcur + (m - lg2(ss));
            const bool valid = (unsigned)(d - row) < 256u;        // 0 <= j < 256
            const float Rn = valid ? rv : BIGF;
            float ha = e3 * h1; ha = fmaf(e2, Hu, ha); ha = fmaf(e1, Hd, ha);
            const float Hn = fmaf(ri, ha, 1.0f);
            float ga = e3 * g1; ga = fmaf(e2, Gu, ga); ga = fmaf(e1, Gd, ga);
            const float Gn = fmaf(ri, ga, fwv * fwv);
            // boundary export for next diagonals
            const float nR = __shfl_up(Rn, 1);
            const float nH = __shfl_up(Hn, 1);
            const float nG = __shfl_up(Gn, 1);
            if (lane63) ring[d & 63][w] = make_float4(Rn, Hn, Gn, 0.f);
            // shift state
            rp2 = rp1; rp1 = Rn; h2 = h1; h1 = Hn; g2 = g1; g1 = Gn;
            uR2 = uR; uR = nR; uH2 = uH; uH = nH; uG2 = uG; uG = nG;
            c1 = BIGF;
            fwv -= 1.0f;
        }
        rcarry = rstage[15];
#pragma unroll
        for (int k = 0; k < 16; ++k) dstA[k] = dstB[k];
        __syncthreads();
    }

    // wave 3 lane 63 (row 255): after final phase (d=511 dummy), d-1 state = diag 510
    if (tid == 255) {
        g_shape[b] = rp2;    // R'(255,255)
        g_sumE[b]  = h2;     // sum(E)
        g_sumEw[b] = g2;     // sum(E * (i-j)^2)
    }
}

// ---------------------------------------------------------------------------
// Kernel 3: finalize scalar loss.
// ---------------------------------------------------------------------------
__global__ __launch_bounds__(128) void fin_kernel(float* __restrict__ out) {
    __shared__ float rs[128];
    __shared__ float rt2[128];
    const int b = threadIdx.x;

    const float shape = g_shape[b] * GLN2 * (1.0f / (float)TT);

    const float sE  = g_sumE[b]  * (1.0f / (float)TT);
    const float sEw = g_sumEw[b] * (1.0f / (float)TT) * (1.0f / (255.0f * 255.0f));
    const float temporal = sEw / fmaxf(sE, 1e-8f);

    rs[b]  = shape;
    rt2[b] = temporal;
    __syncthreads();
    for (int s = 64; s > 0; s >>= 1) {
        if (b < s) { rs[b] += rs[b + s]; rt2[b] += rt2[b + s]; }
        __syncthreads();
    }
    if (b == 0) {
        out[0] = 0.5f * (rs[0] * (1.0f / (float)BB)) + 0.5f * (rt2[0] * (1.0f / (float)BB));
    }
}

extern "C" void kernel_launch(void* const* d_in, const int* in_sizes, int n_in,
                              void* d_out, int out_size, void* d_ws, size_t ws_size,
                              hipStream_t stream) {
    (void)in_sizes; (void)n_in; (void)out_size; (void)d_ws; (void)ws_size;
    const float* preds   = (const float*)d_in[0];
    const float* targets = (const float*)d_in[1];
    float* out = (float*)d_out;

    dist_kernel<<<dim3(4, 4, BB), 256, 0, stream>>>(preds, targets);
    scan_kernel<<<BB, 256, 0, stream>>>();
    fin_kernel<<<1, 128, 0, stream>>>(out);
}